// Round 7
// baseline (926.578 us; speedup 1.0000x reference)
//
#include <hip/hip_runtime.h>
#include <hip/hip_bf16.h>
#include <math.h>

#define Bsz 512
#define Hd 1024
#define Vd 512
#define Cc 128
#define Ll 120
#define Kk 10
#define Oo 32
#define NSTEP 30

typedef __attribute__((ext_vector_type(8))) short bf16x8;
typedef __attribute__((ext_vector_type(4))) float f32x4;
typedef unsigned short ushort;
typedef unsigned long long u64;

static __device__ __forceinline__ float sigm(float x) { return 1.f / (1.f + expf(-x)); }
static __device__ __forceinline__ ushort f2bf(float x) {
    __hip_bfloat16 h = __float2bfloat16(x);
    return *(ushort*)&h;
}
static __device__ __forceinline__ float bf2f(ushort u) {
    __hip_bfloat16 h; *(ushort*)&h = u;
    return __bfloat162float(h);
}
// monotone float->uint map: a > b  <=>  mono(a) > mono(b)
static __device__ __forceinline__ unsigned monofy(float f) {
    unsigned u = __float_as_uint(f);
    return (u & 0x80000000u) ? ~u : (u | 0x80000000u);
}

// ---------- split f32 -> hi/lo bf16 elementwise ----------
__global__ void k_split(const float* __restrict__ in, ushort* __restrict__ hi,
                        ushort* __restrict__ lo, int n) {
    int i = blockIdx.x * 256 + threadIdx.x;
    if (i < n) {
        float v = in[i];
        ushort h = f2bf(v);
        hi[i] = h;
        lo[i] = f2bf(v - bf2f(h));
    }
}

// ---------- pack + split W[N][1024] into MFMA frag layout ----------
// flat = ((nf*32 + c)*64 + l)*8 + jj ; element = W[nf*16 + (l&15)][c*32 + (l>>4)*8 + jj]
__global__ void k_pack(const float* __restrict__ W, ushort* __restrict__ hi,
                       ushort* __restrict__ lo, int total) {
    int idx = blockIdx.x * 256 + threadIdx.x;
    if (idx >= total) return;
    int jj = idx & 7, l = (idx >> 3) & 63, c = (idx >> 9) & 31, nf = idx >> 14;
    int n = nf * 16 + (l & 15);
    int k = c * 32 + ((l >> 4) << 3) + jj;
    float v = W[(size_t)n * 1024 + k];
    ushort h = f2bf(v);
    hi[idx] = h;
    lo[idx] = f2bf(v - bf2f(h));
}

// ---------- pack conv_w [O,C,K] into B-frag layout over K'=(kconv,c)=1280 ----------
__global__ void k_packconv(const float* __restrict__ cw, ushort* __restrict__ hi,
                           ushort* __restrict__ lo) {
    int idx = blockIdx.x * 256 + threadIdx.x;
    if (idx >= 2 * 40 * 64 * 8) return;
    int jj = idx & 7, l = (idx >> 3) & 63, ch = (idx >> 9) % 40, nf = idx / (40 * 512);
    int o = nf * 16 + (l & 15);
    int k = ch * 32 + ((l >> 4) << 3) + jj;
    int kc = k >> 7, c = k & 127;
    float v = cw[(o * Cc + c) * Kk + kc];
    ushort h = f2bf(v);
    hi[idx] = h;
    lo[idx] = f2bf(v - bf2f(h));
}

// ---------- conv as MFMA GEMM (M=t, N=32 o, K=1280) + masked max + encoder FC ----------
// 256 blocks x 2 batches each: 32 slabs/XCD -> per-XCD L2 footprint 2 MB (was 3.9, thrash)
__global__ __launch_bounds__(256) void k_convmfma(const ushort* __restrict__ xH,
                                                  const ushort* __restrict__ xL,
                                                  const ushort* __restrict__ wH,
                                                  const ushort* __restrict__ wL,
                                                  const float* __restrict__ cb,
                                                  const float* __restrict__ ew,
                                                  const float* __restrict__ eb,
                                                  float* __restrict__ h0,
                                                  ushort* __restrict__ ApHi,
                                                  ushort* __restrict__ ApLo) {
    __shared__ float sred[4][2][16];
    __shared__ float ps[Oo];
    int tid = threadIdx.x, wid = tid >> 6, l = tid & 63;

    for (int b2 = 0; b2 < 2; ++b2) {
        int b = blockIdx.x * 2 + b2;
        f32x4 acc[2][2];
#pragma unroll
        for (int i = 0; i < 2; ++i)
#pragma unroll
            for (int j = 0; j < 2; ++j) acc[i][j] = (f32x4)0.f;

        bf16x8 aH0[2], aL0[2], bH0[2], bL0[2];
        bf16x8 aH1[2], aL1[2], bH1[2], bL1[2];

#define CLD(AH, AL, BH, BL, ch)                                                        \
    {                                                                                  \
        _Pragma("unroll") for (int tf2 = 0; tf2 < 2; ++tf2) {                          \
            int aoff = ((b * 120 + (wid * 2 + tf2) * 16 + (l & 15) + ((ch) >> 2)) * 128 \
                        + ((ch) & 3) * 32 + ((l >> 4) << 3));                          \
            AH[tf2] = *(const bf16x8*)(xH + aoff);                                     \
            AL[tf2] = *(const bf16x8*)(xL + aoff);                                     \
        }                                                                              \
        _Pragma("unroll") for (int nf = 0; nf < 2; ++nf) {                             \
            int boff = ((nf * 40 + (ch)) * 64 + l) * 8;                                \
            BH[nf] = *(const bf16x8*)(wH + boff);                                      \
            BL[nf] = *(const bf16x8*)(wL + boff);                                      \
        }                                                                              \
    }
#define CST(AH, AL, BH, BL)                                                            \
    {                                                                                  \
        _Pragma("unroll") for (int tf2 = 0; tf2 < 2; ++tf2)                            \
            _Pragma("unroll") for (int nf = 0; nf < 2; ++nf) {                         \
                acc[tf2][nf] = __builtin_amdgcn_mfma_f32_16x16x32_bf16(                \
                    AH[tf2], BH[nf], acc[tf2][nf], 0, 0, 0);                           \
                acc[tf2][nf] = __builtin_amdgcn_mfma_f32_16x16x32_bf16(                \
                    AH[tf2], BL[nf], acc[tf2][nf], 0, 0, 0);                           \
                acc[tf2][nf] = __builtin_amdgcn_mfma_f32_16x16x32_bf16(                \
                    AL[tf2], BH[nf], acc[tf2][nf], 0, 0, 0);                           \
            }                                                                          \
    }

        CLD(aH0, aL0, bH0, bL0, 0)
#pragma unroll
        for (int ch = 0; ch < 40; ch += 2) {
            CLD(aH1, aL1, bH1, bL1, ch + 1)
            CST(aH0, aL0, bH0, bL0)
            if (ch + 2 < 40) CLD(aH0, aL0, bH0, bL0, ch + 2)
            CST(aH1, aL1, bH1, bL1)
        }
#undef CLD
#undef CST

        float mx[2] = {-1e38f, -1e38f};
#pragma unroll
        for (int tf2 = 0; tf2 < 2; ++tf2) {
            int tb = (wid * 2 + tf2) * 16 + ((l >> 4) << 2);
#pragma unroll
            for (int q = 0; q < 4; ++q) {
                if (tb + q <= 110) {
                    mx[0] = fmaxf(mx[0], acc[tf2][0][q]);
                    mx[1] = fmaxf(mx[1], acc[tf2][1][q]);
                }
            }
        }
#pragma unroll
        for (int s = 16; s < 64; s <<= 1) {
            mx[0] = fmaxf(mx[0], __shfl_xor(mx[0], s));
            mx[1] = fmaxf(mx[1], __shfl_xor(mx[1], s));
        }
        if (l < 16) {
            sred[wid][0][l] = mx[0];
            sred[wid][1][l] = mx[1];
        }
        __syncthreads();
        if (tid < Oo) {
            float m = sred[0][tid >> 4][tid & 15];
#pragma unroll
            for (int w = 1; w < 4; ++w) m = fmaxf(m, sred[w][tid >> 4][tid & 15]);
            ps[tid] = fmaxf(m + cb[tid], 0.f);
        }
        __syncthreads();
        for (int j = tid; j < Hd; j += 256) {
            float a = eb[j];
            const float4* e4 = (const float4*)(ew + (size_t)j * Oo);
#pragma unroll
            for (int c4 = 0; c4 < 8; ++c4) {
                float4 w = e4[c4];
                a += ps[c4 * 4 + 0] * w.x + ps[c4 * 4 + 1] * w.y +
                     ps[c4 * 4 + 2] * w.z + ps[c4 * 4 + 3] * w.w;
            }
            a = fmaxf(a, 0.f);
            h0[(size_t)b * Hd + j] = a;
            ushort hb = f2bf(a);
            ushort lb = f2bf(a - bf2f(hb));
            int c = j >> 5, sub = (j >> 3) & 3, jj = j & 7, mf = b >> 4;
            int lane_r = (b & 15) + (sub << 4);
            int flat = ((mf * 32 + c) * 64 + lane_r) * 8 + jj;
            ApHi[flat] = hb;
            ApLo[flat] = lb;
        }
        __syncthreads();   // before next b2 reuses sred/ps
    }
}

// ---------- recurrent GEMM: C[512 x 3x1024] = A @ W^T, B LDS-staged (48 KB dbuf) ----------
// EPI 0: gi table. EPI 1: GRU gates -> h + packed A; decodes token from packed argmax
// cells, writes decoded_indices row, resets the other P buffer.
template <int EPI>
__global__ __launch_bounds__(512, 4) void k_rnn(const ushort* __restrict__ Ah,
                                                const ushort* __restrict__ Al,
                                                const ushort* __restrict__ Bh,
                                                const ushort* __restrict__ Bl,
                                                const float* __restrict__ bias,
                                                float* __restrict__ outF,
                                                const float* __restrict__ gi_all,
                                                const u64* __restrict__ pkRd,
                                                u64* __restrict__ pkWr,
                                                float* __restrict__ outIdxRow,
                                                const float* __restrict__ hOld,
                                                ushort* __restrict__ ApHi,
                                                ushort* __restrict__ ApLo) {
    __shared__ ushort Bs[2][24][512];   // 48 KB: 2 blocks/CU
    int id = blockIdx.x;
    int xcd = id & 7, r = id >> 3;
    int jt = xcd * 4 + (r & 3);
    int mt = r >> 2;
    int tid = threadIdx.x, wid = tid >> 6, l = tid & 63;
    int wm = wid >> 1, wj = wid & 1;
    int mf = mt * 4 + wm;
    int jf = jt * 2 + wj;
    int jcol = jf * 16 + (l & 15);

    float giR[4][3], hR[4];
    int bR[4], tkR[4];
    if constexpr (EPI == 1) {
#pragma unroll
        for (int q = 0; q < 4; ++q) {
            bR[q] = mf * 16 + ((l >> 4) << 2) + q;
            u64 pk = pkRd[bR[q]];
            tkR[q] = 511 - (int)(unsigned)(pk & 0xFFFFFFFFu);
            const float* gi = gi_all + (size_t)tkR[q] * 3072;
            giR[q][0] = gi[jcol];
            giR[q][1] = gi[1024 + jcol];
            giR[q][2] = gi[2048 + jcol];
            hR[q] = hOld[(size_t)bR[q] * 1024 + jcol];
        }
        // designated writers: 8 blocks (jt==0), wave wj==0, lane l&15==0 -> cover all b
        if (jt == 0 && wj == 0 && (l & 15) == 0) {
#pragma unroll
            for (int q = 0; q < 4; ++q) {
                pkWr[bR[q]] = 0ULL;                       // reset next argmax buffer
                if (outIdxRow) outIdxRow[bR[q]] = (float)tkR[q];
            }
        }
    }

    f32x4 acc[3];
#pragma unroll
    for (int g = 0; g < 3; ++g) acc[g] = (f32x4)0.f;

    bf16x8 stg[3], aH0[2], aL0[2], aH1[2], aL1[2];

#define STG_LD(it)                                                                     \
    {                                                                                  \
        _Pragma("unroll") for (int k = 0; k < 3; ++k) {                                \
            int u = wid + 8 * k;                                                       \
            int hl = u & 1, wjb = (u >> 1) & 1, g = (u >> 2) % 3, cu = u / 12;         \
            const ushort* sp = hl ? Bl : Bh;                                           \
            stg[k] = *(const bf16x8*)(sp +                                             \
                (size_t)(((g * 64 + jt * 2 + wjb) * 32 + (it) * 2 + cu) * 64 + l) * 8);\
        }                                                                              \
    }
#define STG_WR(buf)                                                                    \
    {                                                                                  \
        _Pragma("unroll") for (int k = 0; k < 3; ++k)                                  \
            *(bf16x8*)&Bs[buf][wid + 8 * k][l * 8] = stg[k];                           \
    }
#define A_LD(DH, DL, it)                                                               \
    {                                                                                  \
        _Pragma("unroll") for (int cc = 0; cc < 2; ++cc) {                             \
            DH[cc] = *(const bf16x8*)(Ah + (size_t)((mf * 32 + (it) * 2 + cc) * 64 + l) * 8); \
            DL[cc] = *(const bf16x8*)(Al + (size_t)((mf * 32 + (it) * 2 + cc) * 64 + l) * 8); \
        }                                                                              \
    }
#define CMP(buf, AH, AL)                                                               \
    {                                                                                  \
        _Pragma("unroll") for (int cc = 0; cc < 2; ++cc)                               \
            _Pragma("unroll") for (int g = 0; g < 3; ++g) {                            \
                bf16x8 bhh = *(const bf16x8*)&Bs[buf][cc * 12 + g * 4 + wj * 2 + 0][l * 8]; \
                bf16x8 bll = *(const bf16x8*)&Bs[buf][cc * 12 + g * 4 + wj * 2 + 1][l * 8]; \
                acc[g] = __builtin_amdgcn_mfma_f32_16x16x32_bf16(AH[cc], bhh, acc[g], 0, 0, 0); \
                acc[g] = __builtin_amdgcn_mfma_f32_16x16x32_bf16(AH[cc], bll, acc[g], 0, 0, 0); \
                acc[g] = __builtin_amdgcn_mfma_f32_16x16x32_bf16(AL[cc], bhh, acc[g], 0, 0, 0); \
            }                                                                          \
    }

    STG_LD(0)
    STG_WR(0)
    STG_LD(1)
    A_LD(aH0, aL0, 0)
    __syncthreads();
#pragma unroll
    for (int it = 0; it < 16; ++it) {
        int buf = it & 1;
        if (it < 15) STG_WR(buf ^ 1)
        if (it < 14) STG_LD(it + 2)
        if (it & 1) {
            if (it < 15) A_LD(aH0, aL0, it + 1)
            CMP(buf, aH1, aL1)
        } else {
            if (it < 15) A_LD(aH1, aL1, it + 1)
            CMP(buf, aH0, aL0)
        }
        __syncthreads();
    }
#undef STG_LD
#undef STG_WR
#undef A_LD
#undef CMP

    if constexpr (EPI == 0) {
#pragma unroll
        for (int q = 0; q < 4; ++q) {
            int b = mf * 16 + ((l >> 4) << 2) + q;
#pragma unroll
            for (int g = 0; g < 3; ++g)
                outF[(size_t)b * 3072 + g * 1024 + jcol] =
                    acc[g][q] + bias[g * 1024 + jcol];
        }
    } else {
        float bj0 = bias[jcol], bj1 = bias[1024 + jcol], bj2 = bias[2048 + jcol];
        int c = jcol >> 5, sub = (jcol >> 3) & 3, jj = jcol & 7;
#pragma unroll
        for (int q = 0; q < 4; ++q) {
            int b = bR[q];
            float rr = sigm(giR[q][0] + acc[0][q] + bj0);
            float zz = sigm(giR[q][1] + acc[1][q] + bj1);
            float nn = tanhf(giR[q][2] + rr * (acc[2][q] + bj2));
            float hv = (1.f - zz) * nn + zz * hR[q];
            outF[(size_t)b * 1024 + jcol] = hv;
            ushort hb = f2bf(hv);
            ushort lb = f2bf(hv - bf2f(hb));
            int lane_r = (b & 15) + (sub << 4);
            int flat = ((mf * 32 + c) * 64 + lane_r) * 8 + jj;
            ApHi[flat] = hb;
            ApLo[flat] = lb;
        }
    }
}

// ---------- logits GEMM + fused wave-argmax (packed atomicMax) ----------
__global__ __launch_bounds__(256) void k_lgt(const ushort* __restrict__ Ah,
                                             const ushort* __restrict__ Al,
                                             const ushort* __restrict__ Bh,
                                             const ushort* __restrict__ Bl,
                                             const float* __restrict__ bias,
                                             float* __restrict__ outF,
                                             u64* __restrict__ pkOut) {
    int p = blockIdx.x * 4 + (threadIdx.x >> 6);   // 0..1023
    int l = threadIdx.x & 63;
    int mf = p >> 5, vf = p & 31;
    size_t ab = (size_t)(mf * 32) * 512 + l * 8;
    size_t bb = (size_t)(vf * 32) * 512 + l * 8;
    f32x4 acc = (f32x4)0.f;
    bf16x8 a0h, a0l, b0h, b0l, a1h, a1l, b1h, b1l;

#define LD1(AH, AL, BH, BL, c)                                                         \
    {                                                                                  \
        AH = *(const bf16x8*)(Ah + ab + (size_t)(c) * 512);                            \
        AL = *(const bf16x8*)(Al + ab + (size_t)(c) * 512);                            \
        BH = *(const bf16x8*)(Bh + bb + (size_t)(c) * 512);                            \
        BL = *(const bf16x8*)(Bl + bb + (size_t)(c) * 512);                            \
    }
#define ST1(AH, AL, BH, BL)                                                            \
    {                                                                                  \
        acc = __builtin_amdgcn_mfma_f32_16x16x32_bf16(AH, BH, acc, 0, 0, 0);           \
        acc = __builtin_amdgcn_mfma_f32_16x16x32_bf16(AH, BL, acc, 0, 0, 0);           \
        acc = __builtin_amdgcn_mfma_f32_16x16x32_bf16(AL, BH, acc, 0, 0, 0);           \
    }

    LD1(a0h, a0l, b0h, b0l, 0)
#pragma unroll
    for (int c = 0; c < 32; c += 2) {
        LD1(a1h, a1l, b1h, b1l, c + 1)
        ST1(a0h, a0l, b0h, b0l)
        if (c + 2 < 32) LD1(a0h, a0l, b0h, b0l, c + 2)
        ST1(a1h, a1l, b1h, b1l)
    }
#undef LD1
#undef ST1

    int v = vf * 16 + (l & 15);
    float bv = bias[v];
    float lg[4];
    unsigned vmq[4];
#pragma unroll
    for (int q = 0; q < 4; ++q) {
        int b = mf * 16 + ((l >> 4) << 2) + q;
        lg[q] = acc[q] + bv;
        outF[(size_t)b * Vd + v] = lg[q];
        vmq[q] = 511u - (unsigned)v;               // tie-break: larger = lower v
    }
    // argmax over the 16 v's in this tile (within each 16-lane group)
#pragma unroll
    for (int off = 1; off < 16; off <<= 1) {
#pragma unroll
        for (int q = 0; q < 4; ++q) {
            float og = __shfl_xor(lg[q], off);
            unsigned ov = __shfl_xor(vmq[q], off);
            if (og > lg[q] || (og == lg[q] && ov > vmq[q])) { lg[q] = og; vmq[q] = ov; }
        }
    }
    if ((l & 15) == 0) {
#pragma unroll
        for (int q = 0; q < 4; ++q) {
            int b = mf * 16 + ((l >> 4) << 2) + q;
            u64 pk = ((u64)monofy(lg[q]) << 32) | (u64)vmq[q];
            atomicMax(&pkOut[b], pk);
        }
    }
}

// ---------- final: log_softmax of last logits + decoded_indices row 30 ----------
__global__ __launch_bounds__(64) void k_fin(const float* __restrict__ logits,
                                            const u64* __restrict__ pk,
                                            float* __restrict__ out_lsm,
                                            float* __restrict__ outIdxRow) {
    int b = blockIdx.x, l = threadIdx.x;
    const float* row = logits + (size_t)b * Vd;
    float bv = -3.4e38f;
#pragma unroll
    for (int s = 0; s < 8; ++s) bv = fmaxf(bv, row[s * 64 + l]);
#pragma unroll
    for (int off = 1; off < 64; off <<= 1) bv = fmaxf(bv, __shfl_xor(bv, off));
    float sum = 0.f;
#pragma unroll
    for (int s = 0; s < 8; ++s) sum += expf(row[s * 64 + l] - bv);
#pragma unroll
    for (int off = 1; off < 64; off <<= 1) sum += __shfl_xor(sum, off);
    float lse = logf(sum) + bv;
#pragma unroll
    for (int s = 0; s < 8; ++s) {
        int v = s * 64 + l;
        out_lsm[(size_t)b * Vd + v] = row[v] - lse;
    }
    if (l == 0)
        outIdxRow[b] = (float)(511 - (int)(unsigned)(pk[b] & 0xFFFFFFFFu));
}

__global__ void k_init(u64* __restrict__ P0, float* __restrict__ out_idx0) {
    int i = blockIdx.x * 64 + threadIdx.x;
    if (i < Bsz) {
        P0[i] = (1ULL << 32) | 511ULL;   // decodes to token 0 (SOS)
        out_idx0[i] = 0.f;
    }
}

extern "C" void kernel_launch(void* const* d_in, const int* in_sizes, int n_in,
                              void* d_out, int out_size, void* d_ws, size_t ws_size,
                              hipStream_t stream) {
    const float* sm    = (const float*)d_in[0];
    const float* emb   = (const float*)d_in[1];
    const float* w_ih  = (const float*)d_in[2];
    const float* w_hh  = (const float*)d_in[3];
    const float* b_ih  = (const float*)d_in[4];
    const float* b_hh  = (const float*)d_in[5];
    const float* w_out = (const float*)d_in[6];
    const float* b_out = (const float*)d_in[7];
    const float* cw    = (const float*)d_in[8];
    const float* cb    = (const float*)d_in[9];
    const float* ew    = (const float*)d_in[10];
    const float* eb    = (const float*)d_in[11];

    float* out0 = (float*)d_out;                   // decoder_output  [512,512]
    float* out1 = out0 + (size_t)Bsz * Vd;         // decoder_hidden  [30,512,1024]
    float* out2 = out1 + (size_t)NSTEP * Bsz * Hd; // decoded_indices [31,512]

    const int SMN = Bsz * Ll * Cc;                 // 7864320
    char* wsp = (char*)d_ws;
    float*  f_gi  = (float*)wsp;  wsp += sizeof(float) * Bsz * 3072;
    float*  f_h0  = (float*)wsp;  wsp += sizeof(float) * Bsz * Hd;
    float*  f_log = (float*)wsp;  wsp += sizeof(float) * Bsz * Vd;
    u64*    Ppk0  = (u64*)wsp;    wsp += sizeof(u64) * Bsz;
    u64*    Ppk1  = (u64*)wsp;    wsp += sizeof(u64) * Bsz;
    ushort* ApHi0 = (ushort*)wsp; wsp += sizeof(ushort) * Bsz * Hd;
    ushort* ApLo0 = (ushort*)wsp; wsp += sizeof(ushort) * Bsz * Hd;
    ushort* ApHi1 = (ushort*)wsp; wsp += sizeof(ushort) * Bsz * Hd;
    ushort* ApLo1 = (ushort*)wsp; wsp += sizeof(ushort) * Bsz * Hd;
    ushort* embH  = (ushort*)wsp; wsp += sizeof(ushort) * Vd * Hd;
    ushort* embL  = (ushort*)wsp; wsp += sizeof(ushort) * Vd * Hd;
    ushort* wihH  = (ushort*)wsp; wsp += sizeof(ushort) * 3072 * Hd;
    ushort* wihL  = (ushort*)wsp; wsp += sizeof(ushort) * 3072 * Hd;
    ushort* whhH  = (ushort*)wsp; wsp += sizeof(ushort) * 3072 * Hd;
    ushort* whhL  = (ushort*)wsp; wsp += sizeof(ushort) * 3072 * Hd;
    ushort* woutH = (ushort*)wsp; wsp += sizeof(ushort) * Vd * Hd;
    ushort* woutL = (ushort*)wsp; wsp += sizeof(ushort) * Vd * Hd;
    ushort* smH   = (ushort*)wsp; wsp += sizeof(ushort) * (SMN + 32 * Cc);
    ushort* smL   = (ushort*)wsp; wsp += sizeof(ushort) * (SMN + 32 * Cc);
    ushort* cwBH  = (ushort*)wsp; wsp += sizeof(ushort) * 2 * 40 * 64 * 8;
    ushort* cwBL  = (ushort*)wsp; wsp += sizeof(ushort) * 2 * 40 * 64 * 8;

    // one-time setup
    k_split<<<SMN / 256, 256, 0, stream>>>(sm, smH, smL, SMN);
    k_packconv<<<160, 256, 0, stream>>>(cw, cwBH, cwBL);
    k_pack<<<(3072 * 1024) / 256, 256, 0, stream>>>(w_ih, wihH, wihL, 3072 * 1024);
    k_pack<<<(3072 * 1024) / 256, 256, 0, stream>>>(w_hh, whhH, whhL, 3072 * 1024);
    k_pack<<<(512 * 1024) / 256, 256, 0, stream>>>(w_out, woutH, woutL, 512 * 1024);
    k_pack<<<(512 * 1024) / 256, 256, 0, stream>>>(emb, embH, embL, 512 * 1024);
    k_convmfma<<<256, 256, 0, stream>>>(smH, smL, cwBH, cwBL, cb, ew, eb,
                                        f_h0, ApHi0, ApLo0);
    k_rnn<0><<<256, 512, 0, stream>>>(embH, embL, wihH, wihL, b_ih, f_gi,
                                      nullptr, nullptr, nullptr, nullptr, nullptr,
                                      nullptr, nullptr);
    k_init<<<8, 64, 0, stream>>>(Ppk0, out2);

    ushort* aH[2] = {ApHi0, ApHi1};
    ushort* aL[2] = {ApLo0, ApLo1};
    u64* P[2] = {Ppk0, Ppk1};
    for (int t = 0; t < NSTEP; ++t) {
        int cur = t & 1, nxt = cur ^ 1;
        const float* hOld = (t == 0) ? f_h0 : (out1 + (size_t)(t - 1) * Bsz * Hd);
        k_rnn<1><<<256, 512, 0, stream>>>(
            aH[cur], aL[cur], whhH, whhL, b_hh, out1 + (size_t)t * Bsz * Hd,
            f_gi, P[t & 1], P[(t + 1) & 1],
            (t >= 1) ? (out2 + (size_t)t * Bsz) : nullptr,
            hOld, aH[nxt], aL[nxt]);
        k_lgt<<<256, 256, 0, stream>>>(aH[nxt], aL[nxt], woutH, woutL, b_out,
                                       f_log, P[(t + 1) & 1]);
    }
    k_fin<<<Bsz, 64, 0, stream>>>(f_log, P[NSTEP & 1], out0,
                                  out2 + (size_t)NSTEP * Bsz);
}